// Round 5
// baseline (721.095 us; speedup 1.0000x reference)
//
#include <hip/hip_runtime.h>
#include <hip/hip_bf16.h>

// LSTM: B=256, T=512, I=256, H=128 (4H=512 gates), then MLP 128->64->32->4.
// ROUND 13: RB=16 LSTM (16 blocks instead of 64) — all 16 MFMA N-columns are
//   real batch rows, so the recurrence needs only 16 CUs; GEMM co-residency
//   on recurrence CUs drops 25%->6%. Chain-split of round 12 reverted
//   (regressed ~5us/dispatch). Schedule unchanged (conv; skewed fused; head).
//
//   NEW gx layout (built for RB=16 lane reads):
//     idx(g,t,blk,w,n,u) = ((g*TC+t)*16 + blk)*2048 + w*256 + n*16 + u
//     blk=batch>>4, n=batch&15, w=unit>>4, u=unit&15.
//   LSTM lane (n=lane&15, quad=lane>>4) of wave w owns batch b0+n, units
//   16w+4quad+{0..3} (= D rows 4quad+reg, col n): one uint2 gx load per
//   plane per step; h write = one ds_write_b64; exact cover, no dup lanes.
//   GEMM epilogue: 32 x 2B stores (16-lane contiguous 32B runs) — the
//   transpose cost lives on the GEMM side, which has ~2x slack.

#define TC       64
#define NCHUNK   8
#define BATCH    256
#define TSEQ     512
#define ISZ      256
#define HSZ      128
#define RB       16
#define NLB      (BATCH / RB)     // 16 lstm blocks
#define NGB      (2 * TC * 4)     // 512 gemm blocks
#define HROW     136              // shorts; 272B row: lanes n,n+8 2-way only
#define GX_PER_T 131072           // gx elements per timestep (all 4 planes)
#define GXCH     ((size_t)TC * GX_PER_T)   // shorts per gx buffer
#define STRT     32768            // per-plane step stride in shorts (16*2048)
#define PF       4                // gx prefetch depth in steps

#define XN       (BATCH * TSEQ * ISZ)   // 33554432 x elems
#define WIHN     (4 * HSZ * ISZ)        // 131072
#define WHHN     (4 * HSZ * HSZ)        // 65536
#define CVT_UNITS ((XN + WIHN + WHHN) / 8)

typedef __attribute__((ext_vector_type(8))) short short8;
typedef __attribute__((ext_vector_type(4))) float f32x4;

__device__ __forceinline__ void barrier_nodrain() {
    // s_barrier WITHOUT the compiler's vmcnt(0) drain: LDS consistency only.
    __asm__ __volatile__("s_waitcnt lgkmcnt(0)\n\ts_barrier" ::: "memory");
}

__device__ __forceinline__ float fast_rcp(float x) {
    return __builtin_amdgcn_rcpf(x);
}
__device__ __forceinline__ float sigmoidf_(float x) {
    return fast_rcp(1.0f + __expf(-x));
}
__device__ __forceinline__ float tanhf_(float x) {
    float e = __expf(2.0f * x);               // inf-safe
    return 1.0f - 2.0f * fast_rcp(e + 1.0f);
}
__device__ __forceinline__ unsigned short f2bf(float x) {  // fp32 -> bf16 RNE
    union { float f; unsigned u; } v; v.f = x;
    unsigned r = v.u + 0x7fffu + ((v.u >> 16) & 1u);
    return (unsigned short)(r >> 16);
}
__device__ __forceinline__ float bfhalf(unsigned wv, int hi) { // bf16 half->f32
    union { unsigned u; float f; } v;
    v.u = hi ? (wv & 0xffff0000u) : (wv << 16);
    return v.f;
}
__device__ __forceinline__ float bfh4(uint2 v, int r) {   // r-th bf16 of 4
    const unsigned wd = (r & 2) ? v.y : v.x;
    return bfhalf(wd, r & 1);
}
__device__ __forceinline__ unsigned packbf(float lo, float hi) {  // packed HW cvt
    __hip_bfloat162 h2 = __float22bfloat162_rn(make_float2(lo, hi));
    union { __hip_bfloat162 h; unsigned u; } v; v.h = h2;
    return v.u;
}

// ---------------------------------------------------------------------------
// Convert x / Wih / Whh to bf16 workspace copies. Pure BW (~201 MB).
__global__ __launch_bounds__(256) void conv_kernel(
    const float* __restrict__ x, const float* __restrict__ Wih,
    const float* __restrict__ Whh,
    unsigned short* __restrict__ xb, unsigned short* __restrict__ wihb,
    unsigned short* __restrict__ whhb)
{
    const size_t stride = (size_t)gridDim.x * 256;
    for (size_t u = (size_t)blockIdx.x * 256 + threadIdx.x; u < (size_t)CVT_UNITS;
         u += stride) {
        const size_t e0 = u * 8;
        const float* s; unsigned short* d;
        if (e0 < (size_t)XN)               { s = x + e0;                 d = xb + e0; }
        else if (e0 < (size_t)(XN + WIHN)) { s = Wih + (e0 - XN);        d = wihb + (e0 - XN); }
        else                               { s = Whh + (e0 - XN - WIHN); d = whhb + (e0 - XN - WIHN); }
        float4 f0 = *(const float4*)(s);
        float4 f1 = *(const float4*)(s + 4);
        *(uint4*)(d) = (uint4){packbf(f0.x, f0.y), packbf(f0.z, f0.w),
                               packbf(f1.x, f1.y), packbf(f1.z, f1.w)};
    }
}

// ---------------------------------------------------------------------------
// Fused kernel: blocks [0,NLB) lstm (reads gxl), [NLB,..) gemm (writes gxg
// for timestep base t0). Either role can be disabled.
__global__ __launch_bounds__(512, 2) void fused_kernel(
    const unsigned short* __restrict__ xb, const unsigned short* __restrict__ wihb,
    const unsigned short* __restrict__ whhb,
    const float* __restrict__ bih, const float* __restrict__ bhh,
    const unsigned short* __restrict__ gxl, unsigned short* __restrict__ gxg,
    float* __restrict__ hc, int t0, int first, int run_lstm, int run_gemm)
{
    __shared__ __align__(16) char smem[32768];
    const int tid  = threadIdx.x;
    const int w    = tid >> 6;
    const int lane = tid & 63;
    const int n    = lane & 15;
    const int quad = lane >> 4;

    if (blockIdx.x >= NLB) {
        // ===================== GEMM role (gx for chunk at t0) ===============
        if (!run_gemm) return;
        short* As = (short*)smem;            // [2][128*32] bf16, 16 KB
        short* Bs = (short*)(smem + 16384);  // [2][128*32] bf16, 16 KB

        const int gb = (int)blockIdx.x - NLB;
        const int nt = gb & 3;               // gate plane
        const int mt = gb >> 2;
        const int tl = mt >> 1;              // timestep within chunk
        const int b0 = (mt & 1) * 128;       // batch half
        const int n0 = nt * 128;

        const int mq = w & 1;                // wave grid 2(m) x 4(n)
        const int nq = w >> 1;

        const int srow = tid >> 2;           // 0..127 staging row
        const int skh  = (tid & 3) * 8;      // elem offset within 32-k slice

        const unsigned short* xr = xb + ((size_t)(b0 + srow) * TSEQ + (size_t)(t0 + tl)) * ISZ + skh;
        const unsigned short* wr = wihb + (size_t)(n0 + srow) * ISZ + skh;

        f32x4 acc[4][2];
#pragma unroll
        for (int mi = 0; mi < 4; ++mi)
#pragma unroll
            for (int ni = 0; ni < 2; ++ni)
                acc[mi][ni] = (f32x4){0.f, 0.f, 0.f, 0.f};

        *(short8*)(&As[srow * 32 + skh]) = *(const short8*)(xr);
        *(short8*)(&Bs[srow * 32 + skh]) = *(const short8*)(wr);
        barrier_nodrain();

        for (int ks = 0; ks < 8; ++ks) {
            const int cur = (ks & 1) * 4096;
            const int nxt = 4096 - cur;
            short8 va, vb;
            if (ks < 7) {
                va = *(const short8*)(xr + (ks + 1) * 32);
                vb = *(const short8*)(wr + (ks + 1) * 32);
            }
            short8 af[4], bfr[2];
#pragma unroll
            for (int mi = 0; mi < 4; ++mi)
                af[mi] = *(const short8*)(&As[cur + (mq * 64 + mi * 16 + n) * 32 + quad * 8]);
#pragma unroll
            for (int ni = 0; ni < 2; ++ni)
                bfr[ni] = *(const short8*)(&Bs[cur + (nq * 32 + ni * 16 + n) * 32 + quad * 8]);
#pragma unroll
            for (int mi = 0; mi < 4; ++mi)
#pragma unroll
                for (int ni = 0; ni < 2; ++ni)
                    acc[mi][ni] = __builtin_amdgcn_mfma_f32_16x16x32_bf16(
                        af[mi], bfr[ni], acc[mi][ni], 0, 0, 0);
            if (ks < 7) {
                *(short8*)(&As[nxt + srow * 32 + skh]) = va;
                *(short8*)(&Bs[nxt + srow * 32 + skh]) = vb;
            }
            barrier_nodrain();
        }

        // epilogue: bias + bf16, RB=16 layout, 32 x 2B stores (16-lane runs).
        // element (gate j, batch B): ((nt*TC+tl)*16 + B>>4)*2048
        //                            + (j>>4)*256 + (B&15)*16 + (j&15)
#pragma unroll
        for (int ni = 0; ni < 2; ++ni) {
            const int j    = nq * 32 + ni * 16 + n;   // j&15 = n
            const int gate = n0 + j;
            const float bias = bih[gate] + bhh[gate];
            const int W = nq * 2 + ni;                // j >> 4
#pragma unroll
            for (int mi = 0; mi < 4; ++mi) {
                const int blkp = (b0 >> 4) + mq * 4 + mi;   // B>>4 (reg-invariant)
                const size_t tb = (((size_t)nt * TC + tl) * 16 + blkp) * 2048 +
                                  (size_t)W * 256 + (size_t)n;
#pragma unroll
                for (int r = 0; r < 4; ++r)           // B&15 = 4*quad + r
                    gxg[tb + (size_t)(4 * quad + r) * 16] =
                        f2bf(acc[mi][ni][r] + bias);
            }
        }
        return;
    }

    // ======================= LSTM role (RB=16) ==============================
    if (!run_lstm) return;
    __builtin_amdgcn_s_setprio(1);   // latency-critical chain wins issue arb
    short* h_lds = (short*)smem;     // [2][RB][HROW] bf16 double-buffered h

    const int blk = (int)blockIdx.x;     // 0..15
    const int b0  = blk * RB;
    const int ju  = 16 * w + 4 * quad;   // first of this lane's 4 units
    // lane owns batch b0+n, units ju..ju+3 (D rows 4*quad+r, col n)

    // static A-frags straight from pre-converted bf16 Whh
    short8 Af[4][4];
#pragma unroll
    for (int g = 0; g < 4; ++g) {
        const unsigned short* rowb = whhb + (size_t)(128 * g + 16 * w + n) * HSZ + 8 * quad;
#pragma unroll
        for (int ks = 0; ks < 4; ++ks)
            Af[g][ks] = *(const short8*)(rowb + 32 * ks);
    }

    // init unit state (4 consecutive units -> float4 loads, b64 LDS write)
    float cst[4], hl[4];
    {
        uint2 hw = (uint2){0u, 0u};
        if (!first) {
            float4 cv = *(const float4*)(hc + (size_t)BATCH * HSZ + (size_t)(b0 + n) * HSZ + ju);
            float4 hv = *(const float4*)(hc + (size_t)(b0 + n) * HSZ + ju);
            cst[0] = cv.x; cst[1] = cv.y; cst[2] = cv.z; cst[3] = cv.w;
            hw = (uint2){packbf(hv.x, hv.y), packbf(hv.z, hv.w)};
        } else {
            cst[0] = cst[1] = cst[2] = cst[3] = 0.f;
        }
        hl[0] = hl[1] = hl[2] = hl[3] = 0.f;
        *(uint2*)(&h_lds[n * HROW + ju]) = hw;    // buffer 0
    }

    // gx: one uint2 per plane per step (4 units x this lane's batch)
    const unsigned short* gp[4];
#pragma unroll
    for (int g = 0; g < 4; ++g)
        gp[g] = gxl + ((size_t)g * TC * 16 + blk) * 2048 + w * 256 + n * 16 + 4 * quad;

    uint2 gq[PF][4];
#pragma unroll
    for (int d = 0; d < PF; ++d)
#pragma unroll
        for (int g = 0; g < 4; ++g)
            gq[d][g] = *(const uint2*)(gp[g] + (size_t)d * STRT);

    barrier_nodrain();

    for (int t = 0; t < TC; t += PF) {
#pragma unroll
        for (int u = 0; u < PF; ++u) {
            const int tt = t + u;
            const short* hb_r = h_lds + (tt & 1) * (RB * HROW);
            short*       hb_w = h_lds + ((tt & 1) ^ 1) * (RB * HROW);

            short8 Bf[4];
#pragma unroll
            for (int ks = 0; ks < 4; ++ks)
                Bf[ks] = *(const short8*)(&hb_r[n * HROW + 32 * ks + 8 * quad]);

            // MFMAs: zero-C first, 4 independent 4-deep chains (one per gate)
            f32x4 acc[4];
#pragma unroll
            for (int g = 0; g < 4; ++g)
                acc[g] = __builtin_amdgcn_mfma_f32_16x16x32_bf16(
                    Af[g][0], Bf[0], (f32x4){0.f, 0.f, 0.f, 0.f}, 0, 0, 0);
#pragma unroll
            for (int ks = 1; ks < 4; ++ks)
#pragma unroll
                for (int g = 0; g < 4; ++g)
                    acc[g] = __builtin_amdgcn_mfma_f32_16x16x32_bf16(
                        Af[g][ks], Bf[ks], acc[g], 0, 0, 0);

            // reload ring slot u (consumed below) for step tt+PF
            const int tf = (tt + PF < TC) ? (tt + PF) : (TC - 1);
            uint2 gnew[4];
#pragma unroll
            for (int g = 0; g < 4; ++g)
                gnew[g] = *(const uint2*)(gp[g] + (size_t)tf * STRT);

            // 4 independent unit updates (reg r = unit ju+r, batch b0+n)
#pragma unroll
            for (int r = 0; r < 4; ++r) {
                const float s0 = acc[0][r] + bfh4(gq[u][0], r);
                const float s1 = acc[1][r] + bfh4(gq[u][1], r);
                const float s2 = acc[2][r] + bfh4(gq[u][2], r);
                const float s3 = acc[3][r] + bfh4(gq[u][3], r);
                const float ig = sigmoidf_(s0);
                const float fg = sigmoidf_(s1);
                const float gg = tanhf_(s2);
                const float og = sigmoidf_(s3);
                cst[r] = fg * cst[r] + ig * gg;
                hl[r]  = og * tanhf_(cst[r]);
            }
#pragma unroll
            for (int g = 0; g < 4; ++g) gq[u][g] = gnew[g];

            *(uint2*)(&hb_w[n * HROW + ju]) =
                (uint2){packbf(hl[0], hl[1]), packbf(hl[2], hl[3])};
            barrier_nodrain();
        }
    }

    *(float4*)(&hc[(size_t)(b0 + n) * HSZ + ju]) =
        (float4){hl[0], hl[1], hl[2], hl[3]};
    *(float4*)(&hc[(size_t)BATCH * HSZ + (size_t)(b0 + n) * HSZ + ju]) =
        (float4){cst[0], cst[1], cst[2], cst[3]};
}

// ---------------------------------------------------------------------------
// MLP head: one block (64 threads) per batch row.
__global__ __launch_bounds__(64) void head_kernel(
    const float* __restrict__ hc,
    const float* __restrict__ W1, const float* __restrict__ b1,
    const float* __restrict__ W2, const float* __restrict__ b2,
    const float* __restrict__ W3, const float* __restrict__ b3,
    float* __restrict__ out)
{
    __shared__ float hs[HSZ];
    __shared__ float o1[64];
    __shared__ float o2[32];
    const int bidx = blockIdx.x;
    const int t = threadIdx.x;
    hs[t]      = hc[bidx * HSZ + t];
    hs[t + 64] = hc[bidx * HSZ + t + 64];
    __syncthreads();
    {
        float a = b1[t];
#pragma unroll 8
        for (int k = 0; k < HSZ; ++k) a += W1[t * HSZ + k] * hs[k];
        o1[t] = fmaxf(a, 0.0f);
    }
    __syncthreads();
    if (t < 32) {
        float a = b2[t];
#pragma unroll 8
        for (int k = 0; k < 64; ++k) a += W2[t * 64 + k] * o1[k];
        o2[t] = fmaxf(a, 0.0f);
    }
    __syncthreads();
    if (t < 4) {
        float a = b3[t];
#pragma unroll
        for (int k = 0; k < 32; ++k) a += W3[t * 32 + k] * o2[k];
        out[bidx * 4 + t] = a;
    }
}

// ---------------------------------------------------------------------------
extern "C" void kernel_launch(void* const* d_in, const int* in_sizes, int n_in,
                              void* d_out, int out_size, void* d_ws, size_t ws_size,
                              hipStream_t stream) {
    const float* x   = (const float*)d_in[0];
    const float* Wih = (const float*)d_in[1];
    const float* Whh = (const float*)d_in[2];
    const float* bih = (const float*)d_in[3];
    const float* bhh = (const float*)d_in[4];
    const float* W1  = (const float*)d_in[5];
    const float* b1  = (const float*)d_in[6];
    const float* W2  = (const float*)d_in[7];
    const float* b2  = (const float*)d_in[8];
    const float* W3  = (const float*)d_in[9];
    const float* b3  = (const float*)d_in[10];
    float* out = (float*)d_out;

    const size_t GXB = GXCH * sizeof(unsigned short);          // 16.78 MB
    unsigned short* gx0 = (unsigned short*)d_ws;
    unsigned short* gx1 = (unsigned short*)((char*)d_ws + GXB);
    float* hc = (float*)((char*)d_ws + 2 * GXB);               // 256 KB
    unsigned short* xb   = (unsigned short*)((char*)d_ws + 2 * GXB + 262144);
    unsigned short* wihb = xb + (size_t)XN;
    unsigned short* whhb = wihb + WIHN;

    // L0: fp32 -> bf16 conversion (pure BW)
    conv_kernel<<<dim3(2048), 256, 0, stream>>>(x, Wih, Whh, xb, wihb, whhb);

    // L1..L9: skewed pipeline. Launch k: GEMM(chunk k) + LSTM(chunk k-1).
    for (int k = 0; k <= NCHUNK; ++k) {
        const int run_gemm = (k < NCHUNK);
        const int run_lstm = (k > 0);
        unsigned short* gg = (k & 1) ? gx1 : gx0;        // gemm writes chunk k
        const unsigned short* gl = ((k - 1) & 1) ? gx1 : gx0; // lstm reads k-1
        fused_kernel<<<dim3(NLB + NGB), 512, 0, stream>>>(
            xb, wihb, whhb, bih, bhh, gl, gg, hc,
            k * TC, (k == 1) ? 1 : 0, run_lstm, run_gemm);
    }

    head_kernel<<<dim3(BATCH), 64, 0, stream>>>(hc, W1, b1, W2, b2, W3, b3, out);
}

// Round 6
// 560.452 us; speedup vs baseline: 1.2866x; 1.2866x over previous
//
#include <hip/hip_runtime.h>
#include <hip/hip_bf16.h>

// LSTM: B=256, T=512, I=256, H=128 (4H=512 gates), then MLP 128->64->32->4.
// ROUND 14: recombine the two measured wins, revert everything else.
//   * LSTM role: round-2 structure EXACTLY (1 unit/lane, rsel in-lane gate
//     extract, single 4-deep MFMA chains, PF=4 gx ring, 1 barrier/step).
//     Measured deltas: chain-split +40us (r12), 2-group pipeline +600us
//     (r11), RB=16 +150us (r13) -> all reverted.
//   * Schedule: round-4 (conv kernel; skewed fused launches k=0..8 where
//     launch k = GEMM(chunk k) + LSTM(chunk k-1); head).
//
//   gx gate-plane layout (round-2):
//     idx(g,t,blk2,wj,L) = (((g*TC+t)*64 + blk2)*512) + wj*64 + L
//     blk2=batch>>2, j=gate&127, wj=j>>4, L=(j&15)*4+(batch&3).

#define TC       64
#define NCHUNK   8
#define BATCH    256
#define TSEQ     512
#define ISZ      256
#define HSZ      128
#define RB       4
#define NBLK     (BATCH / RB)     // 64 lstm blocks
#define NGB      (2 * TC * 4)     // 512 gemm blocks
#define HROW     144              // shorts; 72 dwords = 8 mod 32 -> 2-way only
#define GX_PER_T 131072           // gx elements per timestep (all 4 planes)
#define GXCH     ((size_t)TC * GX_PER_T)   // shorts per gx buffer
#define STRT     32768            // per-plane step stride in shorts (64*512)
#define PF       4                // gx prefetch depth in steps

#define XN       (BATCH * TSEQ * ISZ)   // 33554432 x elems
#define WIHN     (4 * HSZ * ISZ)        // 131072
#define WHHN     (4 * HSZ * HSZ)        // 65536
#define CVT_UNITS ((XN + WIHN + WHHN) / 8)

typedef __attribute__((ext_vector_type(8))) short short8;
typedef __attribute__((ext_vector_type(4))) float f32x4;

__device__ __forceinline__ void barrier_nodrain() {
    // s_barrier WITHOUT the compiler's vmcnt(0) drain: LDS consistency only.
    __asm__ __volatile__("s_waitcnt lgkmcnt(0)\n\ts_barrier" ::: "memory");
}

__device__ __forceinline__ float fast_rcp(float x) {
    return __builtin_amdgcn_rcpf(x);
}
__device__ __forceinline__ float sigmoidf_(float x) {
    return fast_rcp(1.0f + __expf(-x));
}
__device__ __forceinline__ float tanhf_(float x) {
    float e = __expf(2.0f * x);               // inf-safe
    return 1.0f - 2.0f * fast_rcp(e + 1.0f);
}
__device__ __forceinline__ unsigned short f2bf(float x) {  // fp32 -> bf16 RNE
    union { float f; unsigned u; } v; v.f = x;
    unsigned r = v.u + 0x7fffu + ((v.u >> 16) & 1u);
    return (unsigned short)(r >> 16);
}
__device__ __forceinline__ float bf2f(unsigned short b) {
    union { unsigned u; float f; } v;
    v.u = ((unsigned)b) << 16;
    return v.f;
}
__device__ __forceinline__ unsigned packbf(float lo, float hi) {  // packed HW cvt
    __hip_bfloat162 h2 = __float22bfloat162_rn(make_float2(lo, hi));
    union { __hip_bfloat162 h; unsigned u; } v; v.h = h2;
    return v.u;
}
__device__ __forceinline__ float sel4(f32x4 v, int r) {   // v[r], 3 cndmask
    float s01 = (r & 1) ? v[1] : v[0];
    float s23 = (r & 1) ? v[3] : v[2];
    return (r & 2) ? s23 : s01;
}

// ---------------------------------------------------------------------------
// Convert x / Wih / Whh to bf16 workspace copies. Pure BW (~201 MB).
__global__ __launch_bounds__(256) void conv_kernel(
    const float* __restrict__ x, const float* __restrict__ Wih,
    const float* __restrict__ Whh,
    unsigned short* __restrict__ xb, unsigned short* __restrict__ wihb,
    unsigned short* __restrict__ whhb)
{
    const size_t stride = (size_t)gridDim.x * 256;
    for (size_t u = (size_t)blockIdx.x * 256 + threadIdx.x; u < (size_t)CVT_UNITS;
         u += stride) {
        const size_t e0 = u * 8;
        const float* s; unsigned short* d;
        if (e0 < (size_t)XN)               { s = x + e0;                 d = xb + e0; }
        else if (e0 < (size_t)(XN + WIHN)) { s = Wih + (e0 - XN);        d = wihb + (e0 - XN); }
        else                               { s = Whh + (e0 - XN - WIHN); d = whhb + (e0 - XN - WIHN); }
        float4 f0 = *(const float4*)(s);
        float4 f1 = *(const float4*)(s + 4);
        *(uint4*)(d) = (uint4){packbf(f0.x, f0.y), packbf(f0.z, f0.w),
                               packbf(f1.x, f1.y), packbf(f1.z, f1.w)};
    }
}

// ---------------------------------------------------------------------------
// Fused kernel: blocks [0,NBLK) lstm (reads gxl), [NBLK,..) gemm (writes gxg
// for timestep base t0). Either role can be disabled.
__global__ __launch_bounds__(512, 2) void fused_kernel(
    const unsigned short* __restrict__ xb, const unsigned short* __restrict__ wihb,
    const unsigned short* __restrict__ whhb,
    const float* __restrict__ bih, const float* __restrict__ bhh,
    const unsigned short* __restrict__ gxl, unsigned short* __restrict__ gxg,
    float* __restrict__ hc, int t0, int first, int run_lstm, int run_gemm)
{
    __shared__ __align__(16) char smem[32768];
    const int tid  = threadIdx.x;
    const int w    = tid >> 6;
    const int lane = tid & 63;
    const int n    = lane & 15;
    const int quad = lane >> 4;

    if (blockIdx.x >= NBLK) {
        // ===================== GEMM role (gx for chunk at t0) ===============
        if (!run_gemm) return;
        short* As = (short*)smem;            // [2][128*32] bf16, 16 KB
        short* Bs = (short*)(smem + 16384);  // [2][128*32] bf16, 16 KB

        const int gb = (int)blockIdx.x - NBLK;
        const int nt = gb & 3;               // gate plane
        const int mt = gb >> 2;
        const int tl = mt >> 1;              // timestep within chunk
        const int b0 = (mt & 1) * 128;       // batch half
        const int n0 = nt * 128;

        const int mq = w & 1;                // wave grid 2(m) x 4(n)
        const int nq = w >> 1;

        const int srow = tid >> 2;           // 0..127 staging row
        const int skh  = (tid & 3) * 8;      // elem offset within 32-k slice

        const unsigned short* xr = xb + ((size_t)(b0 + srow) * TSEQ + (size_t)(t0 + tl)) * ISZ + skh;
        const unsigned short* wr = wihb + (size_t)(n0 + srow) * ISZ + skh;

        f32x4 acc[4][2];
#pragma unroll
        for (int mi = 0; mi < 4; ++mi)
#pragma unroll
            for (int ni = 0; ni < 2; ++ni)
                acc[mi][ni] = (f32x4){0.f, 0.f, 0.f, 0.f};

        *(short8*)(&As[srow * 32 + skh]) = *(const short8*)(xr);
        *(short8*)(&Bs[srow * 32 + skh]) = *(const short8*)(wr);
        barrier_nodrain();

        for (int ks = 0; ks < 8; ++ks) {
            const int cur = (ks & 1) * 4096;
            const int nxt = 4096 - cur;
            short8 va, vb;
            if (ks < 7) {
                va = *(const short8*)(xr + (ks + 1) * 32);
                vb = *(const short8*)(wr + (ks + 1) * 32);
            }
            short8 af[4], bfr[2];
#pragma unroll
            for (int mi = 0; mi < 4; ++mi)
                af[mi] = *(const short8*)(&As[cur + (mq * 64 + mi * 16 + n) * 32 + quad * 8]);
#pragma unroll
            for (int ni = 0; ni < 2; ++ni)
                bfr[ni] = *(const short8*)(&Bs[cur + (nq * 32 + ni * 16 + n) * 32 + quad * 8]);
#pragma unroll
            for (int mi = 0; mi < 4; ++mi)
#pragma unroll
                for (int ni = 0; ni < 2; ++ni)
                    acc[mi][ni] = __builtin_amdgcn_mfma_f32_16x16x32_bf16(
                        af[mi], bfr[ni], acc[mi][ni], 0, 0, 0);
            if (ks < 7) {
                *(short8*)(&As[nxt + srow * 32 + skh]) = va;
                *(short8*)(&Bs[nxt + srow * 32 + skh]) = vb;
            }
            barrier_nodrain();
        }

        // epilogue: bias + bf16, gate-plane layout, 8-B contiguous stores.
#pragma unroll
        for (int ni = 0; ni < 2; ++ni) {
            const int j    = nq * 32 + ni * 16 + n;
            const int gate = n0 + j;
            const float bias = bih[gate] + bhh[gate];
            const int wj = nq * 2 + ni;                       // j >> 4
#pragma unroll
            for (int mi = 0; mi < 4; ++mi) {
                const int bb   = b0 + mq * 64 + mi * 16 + quad * 4;
                const int blk2 = bb >> 2;
                const size_t idx = ((((size_t)nt * TC + tl) * 64 + blk2) * 512) +
                                   (size_t)wj * 64 + (size_t)n * 4;
                const unsigned lo = packbf(acc[mi][ni][0] + bias, acc[mi][ni][1] + bias);
                const unsigned hi = packbf(acc[mi][ni][2] + bias, acc[mi][ni][3] + bias);
                *(uint2*)(&gxg[idx]) = (uint2){lo, hi};
            }
        }
        return;
    }

    // ======================= LSTM role (round-2 structure) ==================
    if (!run_lstm) return;
    __builtin_amdgcn_s_setprio(1);   // latency-critical chain wins issue arb
    short* h_lds = (short*)smem;     // [2*RB*HROW] bf16 double-buffered h

    const int blk  = (int)blockIdx.x;
    const int b0   = blk * RB;
    const int nb   = lane & 3;           // unit batch
    const int jl   = lane >> 2;          // unit j-local 0..15
    const int j    = 16 * w + jl;        // unit hidden index
    const int rsel = jl & 3;             // D-reg holding this unit's gate

    // static A-frags straight from pre-converted bf16 Whh
    short8 Af[4][4];
#pragma unroll
    for (int g = 0; g < 4; ++g) {
        const unsigned short* rowb = whhb + (size_t)(128 * g + 16 * w + n) * HSZ + 8 * quad;
#pragma unroll
        for (int ks = 0; ks < 4; ++ks)
            Af[g][ks] = *(const short8*)(rowb + 32 * ks);
    }

    // init unit state: every thread owns one (j, b) unit
    float c1 = 0.f, hl1 = 0.f;
    {
        unsigned short h0 = 0;
        if (!first) {
            c1 = hc[(size_t)BATCH * HSZ + (size_t)(b0 + nb) * HSZ + j];
            h0 = f2bf(hc[(size_t)(b0 + nb) * HSZ + j]);
        }
        *(unsigned short*)&h_lds[nb * HROW + j] = h0;   // buffer 0
    }

    // gx: 4 coalesced ushort loads per lane per step (one per gate plane)
    const unsigned short* gp[4];
#pragma unroll
    for (int g = 0; g < 4; ++g)
        gp[g] = gxl + (((size_t)g * TC) * 64 + blk) * 512 + (size_t)w * 64 + lane;

    unsigned short gq[PF][4];
#pragma unroll
    for (int d = 0; d < PF; ++d)
#pragma unroll
        for (int g = 0; g < 4; ++g)
            gq[d][g] = gp[g][(size_t)d * STRT];

    barrier_nodrain();

    for (int t = 0; t < TC; t += PF) {
#pragma unroll
        for (int u = 0; u < PF; ++u) {
            const int tt = t + u;
            const short* hb_r = h_lds + (u & 1) * (RB * HROW);
            short*       hb_w = h_lds + ((u & 1) ^ 1) * (RB * HROW);

            short8 Bf[4];
#pragma unroll
            for (int ks = 0; ks < 4; ++ks)
                Bf[ks] = *(const short8*)(&hb_r[nb * HROW + 32 * ks + 8 * quad]);

            // MFMAs: zero-C first, 4 independent 4-deep chains (one per gate)
            f32x4 acc[4];
#pragma unroll
            for (int g = 0; g < 4; ++g)
                acc[g] = __builtin_amdgcn_mfma_f32_16x16x32_bf16(
                    Af[g][0], Bf[0], (f32x4){0.f, 0.f, 0.f, 0.f}, 0, 0, 0);
#pragma unroll
            for (int ks = 1; ks < 4; ++ks)
#pragma unroll
                for (int g = 0; g < 4; ++g)
                    acc[g] = __builtin_amdgcn_mfma_f32_16x16x32_bf16(
                        Af[g][ks], Bf[ks], acc[g], 0, 0, 0);

            // in-lane gate extract: unit (jl,nb)'s value is THIS lane's
            // acc[g][rsel] (D row = 4*quad+reg = jl, D col batch = nb).
            const float s0 = sel4(acc[0], rsel) + bf2f(gq[u][0]);
            const float s1 = sel4(acc[1], rsel) + bf2f(gq[u][1]);
            const float s2 = sel4(acc[2], rsel) + bf2f(gq[u][2]);
            const float s3 = sel4(acc[3], rsel) + bf2f(gq[u][3]);

            // reload ring slot u (just consumed) for step tt+PF; vmcnt wait
            // for these loads lands PF steps from now.
            const int tf = (tt + PF < TC) ? (tt + PF) : (TC - 1);
#pragma unroll
            for (int g = 0; g < 4; ++g)
                gq[u][g] = gp[g][(size_t)tf * STRT];

            const float ig = sigmoidf_(s0);
            const float fg = sigmoidf_(s1);
            const float gg = tanhf_(s2);
            const float og = sigmoidf_(s3);
            c1  = fg * c1 + ig * gg;
            hl1 = og * tanhf_(c1);

            *(unsigned short*)&hb_w[nb * HROW + j] = f2bf(hl1);
            barrier_nodrain();
        }
    }

    hc[(size_t)(b0 + nb) * HSZ + j] = hl1;
    hc[(size_t)BATCH * HSZ + (size_t)(b0 + nb) * HSZ + j] = c1;
}

// ---------------------------------------------------------------------------
// MLP head: one block (64 threads) per batch row.
__global__ __launch_bounds__(64) void head_kernel(
    const float* __restrict__ hc,
    const float* __restrict__ W1, const float* __restrict__ b1,
    const float* __restrict__ W2, const float* __restrict__ b2,
    const float* __restrict__ W3, const float* __restrict__ b3,
    float* __restrict__ out)
{
    __shared__ float hs[HSZ];
    __shared__ float o1[64];
    __shared__ float o2[32];
    const int bidx = blockIdx.x;
    const int t = threadIdx.x;
    hs[t]      = hc[bidx * HSZ + t];
    hs[t + 64] = hc[bidx * HSZ + t + 64];
    __syncthreads();
    {
        float a = b1[t];
#pragma unroll 8
        for (int k = 0; k < HSZ; ++k) a += W1[t * HSZ + k] * hs[k];
        o1[t] = fmaxf(a, 0.0f);
    }
    __syncthreads();
    if (t < 32) {
        float a = b2[t];
#pragma unroll 8
        for (int k = 0; k < 64; ++k) a += W2[t * 64 + k] * o1[k];
        o2[t] = fmaxf(a, 0.0f);
    }
    __syncthreads();
    if (t < 4) {
        float a = b3[t];
#pragma unroll
        for (int k = 0; k < 32; ++k) a += W3[t * 32 + k] * o2[k];
        out[bidx * 4 + t] = a;
    }
}

// ---------------------------------------------------------------------------
extern "C" void kernel_launch(void* const* d_in, const int* in_sizes, int n_in,
                              void* d_out, int out_size, void* d_ws, size_t ws_size,
                              hipStream_t stream) {
    const float* x   = (const float*)d_in[0];
    const float* Wih = (const float*)d_in[1];
    const float* Whh = (const float*)d_in[2];
    const float* bih = (const float*)d_in[3];
    const float* bhh = (const float*)d_in[4];
    const float* W1  = (const float*)d_in[5];
    const float* b1  = (const float*)d_in[6];
    const float* W2  = (const float*)d_in[7];
    const float* b2  = (const float*)d_in[8];
    const float* W3  = (const float*)d_in[9];
    const float* b3  = (const float*)d_in[10];
    float* out = (float*)d_out;

    const size_t GXB = GXCH * sizeof(unsigned short);          // 16.78 MB
    unsigned short* gx0 = (unsigned short*)d_ws;
    unsigned short* gx1 = (unsigned short*)((char*)d_ws + GXB);
    float* hc = (float*)((char*)d_ws + 2 * GXB);               // 256 KB
    unsigned short* xb   = (unsigned short*)((char*)d_ws + 2 * GXB + 262144);
    unsigned short* wihb = xb + (size_t)XN;
    unsigned short* whhb = wihb + WIHN;

    // L0: fp32 -> bf16 conversion (pure BW)
    conv_kernel<<<dim3(2048), 256, 0, stream>>>(x, Wih, Whh, xb, wihb, whhb);

    // L1..L9: skewed pipeline. Launch k: GEMM(chunk k) + LSTM(chunk k-1).
    for (int k = 0; k <= NCHUNK; ++k) {
        const int run_gemm = (k < NCHUNK);
        const int run_lstm = (k > 0);
        unsigned short* gg = (k & 1) ? gx1 : gx0;        // gemm writes chunk k
        const unsigned short* gl = ((k - 1) & 1) ? gx1 : gx0; // lstm reads k-1
        fused_kernel<<<dim3(NBLK + NGB), 512, 0, stream>>>(
            xb, wihb, whhb, bih, bhh, gl, gg, hc,
            k * TC, (k == 1) ? 1 : 0, run_lstm, run_gemm);
    }

    head_kernel<<<dim3(BATCH), 64, 0, stream>>>(hc, W1, b1, W2, b2, W3, b3, out);
}